// Round 2
// baseline (5430.692 us; speedup 1.0000x reference)
//
#include <hip/hip_runtime.h>

#define EMB 128

// Step 1: out[r] += ev[e] * X[c]  for each edge; 32 lanes per edge, float4/lane
__global__ __launch_bounds__(256) void scatter_edges(const float* __restrict__ X,
                                                     const float* __restrict__ ev,
                                                     const int* __restrict__ er,
                                                     const int* __restrict__ ec,
                                                     float* __restrict__ out,
                                                     int nedges) {
    const int lane = threadIdx.x & 31;
    long long e = (long long)blockIdx.x * 8 + (threadIdx.x >> 5);
    if (e >= nedges) return;

    const int r = er[e];
    const int c = ec[e];
    const float v = ev[e];

    float4 x = *(const float4*)(X + (size_t)c * EMB + lane * 4);
    float* o = out + (size_t)r * EMB + lane * 4;

    unsafeAtomicAdd(o + 0, v * x.x);
    unsafeAtomicAdd(o + 1, v * x.y);
    unsafeAtomicAdd(o + 2, v * x.z);
    unsafeAtomicAdd(o + 3, v * x.w);
}

// Step 2: out[r,:] = out[r,:] @ W, in place. Row-wise: each block stages its
// 8 rows in LDS before overwriting them; rows are block-disjoint so no
// cross-block hazard.
__global__ __launch_bounds__(256) void gemm_inplace(float* __restrict__ out,
                                                    const float* __restrict__ W,
                                                    int n) {
    __shared__ float Wl[EMB * EMB];   // 64 KB
    __shared__ float Al[8 * EMB];     // 4 KB
    const int tid = threadIdx.x;

    // Stage W once per block (coalesced float4)
    for (int i = tid; i < EMB * EMB / 4; i += 256) {
        ((float4*)Wl)[i] = ((const float4*)W)[i];
    }

    const int j4   = (tid & 31) * 4;  // column base (0..124 step 4)
    const int rsub = tid >> 5;        // 0..7 row within 8-row chunk

    for (int rb = blockIdx.x * 8; rb < n; rb += gridDim.x * 8) {
        __syncthreads();  // Wl ready (first iter) / previous readers done
        {
            int nrows = min(8, n - rb);
            int nfl = nrows * EMB / 4;          // float4 count (<=256)
            if (tid < nfl)
                ((float4*)Al)[tid] = ((const float4*)(out + (size_t)rb * EMB))[tid];
        }
        __syncthreads();

        int r = rb + rsub;
        if (r < n) {
            float4 acc = make_float4(0.f, 0.f, 0.f, 0.f);
            const float* ar = Al + rsub * EMB;
#pragma unroll 4
            for (int k = 0; k < EMB; ++k) {
                float a = ar[k];                                // LDS broadcast
                float4 w = *(const float4*)(Wl + k * EMB + j4); // b128, conflict-free
                acc.x += a * w.x;
                acc.y += a * w.y;
                acc.z += a * w.z;
                acc.w += a * w.w;
            }
            *(float4*)(out + (size_t)r * EMB + j4) = acc;
        }
    }
}

extern "C" void kernel_launch(void* const* d_in, const int* in_sizes, int n_in,
                              void* d_out, int out_size, void* d_ws, size_t ws_size,
                              hipStream_t stream) {
    const float* X  = (const float*)d_in[0];
    const float* W  = (const float*)d_in[1];
    const float* ev = (const float*)d_in[2];
    const int*   er = (const int*)d_in[3];
    const int*   ec = (const int*)d_in[4];

    const int n  = in_sizes[0] / EMB;   // 100000
    const int ne = in_sizes[2];         // 3200000

    float* out = (float*)d_out;

    // out accumulates atomically -> must start from zero every call
    hipMemsetAsync(out, 0, (size_t)n * EMB * sizeof(float), stream);

    const int edges_per_block = 8;  // 256 threads / 32 lanes-per-edge
    int nblk = (ne + edges_per_block - 1) / edges_per_block;
    scatter_edges<<<nblk, 256, 0, stream>>>(X, ev, er, ec, out, ne);

    gemm_inplace<<<2048, 256, 0, stream>>>(out, W, n);
}

// Round 3
// 857.101 us; speedup vs baseline: 6.3361x; 6.3361x over previous
//
#include <hip/hip_runtime.h>
#include <stdint.h>

#define EMB 128

// ---------------- CSR build passes ----------------

__global__ __launch_bounds__(256) void hist_rows(const int* __restrict__ er,
                                                 int* __restrict__ counts, int ne) {
    int i = blockIdx.x * 256 + threadIdx.x;
    int stride = gridDim.x * 256;
    for (; i < ne; i += stride)
        atomicAdd(&counts[er[i]], 1);
}

// Single-block exclusive scan, thread-coarsened by 8 (1024 threads -> 8192/iter)
__global__ __launch_bounds__(1024) void scan_offsets(const int* __restrict__ counts,
                                                     int* __restrict__ off,
                                                     int* __restrict__ cursor, int n) {
    __shared__ int tmp[1024];
    const int tid = threadIdx.x;
    int base = 0;
    for (int start = 0; start < n; start += 1024 * 8) {
        int v[8];
        int local = 0;
        int i0 = start + tid * 8;
#pragma unroll
        for (int j = 0; j < 8; ++j) {
            int i = i0 + j;
            v[j] = (i < n) ? counts[i] : 0;
            local += v[j];
        }
        __syncthreads();              // previous iteration's LDS reads done
        tmp[tid] = local;
        __syncthreads();
#pragma unroll
        for (int d = 1; d < 1024; d <<= 1) {
            int t = (tid >= d) ? tmp[tid - d] : 0;
            __syncthreads();
            tmp[tid] += t;
            __syncthreads();
        }
        int excl = base + tmp[tid] - local;   // exclusive prefix for thread's chunk
        int total = tmp[1023];
#pragma unroll
        for (int j = 0; j < 8; ++j) {
            int i = i0 + j;
            if (i < n) { off[i] = excl; cursor[i] = excl; }
            excl += v[j];
        }
        base += total;
    }
    if (tid == 0) off[n] = base;
}

// Bucket-sort edges by destination row: edge_s[pos] = (col, bits(val))
__global__ __launch_bounds__(256) void sort_edges(const int* __restrict__ er,
                                                  const int* __restrict__ ec,
                                                  const float* __restrict__ ev,
                                                  int* __restrict__ cursor,
                                                  int2* __restrict__ edge_s, int ne) {
    int i = blockIdx.x * 256 + threadIdx.x;
    int stride = gridDim.x * 256;
    for (; i < ne; i += stride) {
        int r = er[i];
        int pos = atomicAdd(&cursor[r], 1);
        edge_s[pos] = make_int2(ec[i], __float_as_int(ev[i]));
    }
}

// ---------------- Pull (one 32-lane group per row, float4/lane) ----------------

__global__ __launch_bounds__(256) void pull_rows(const float* __restrict__ X,
                                                 const int* __restrict__ off,
                                                 const int2* __restrict__ edge_s,
                                                 float* __restrict__ out, int n) {
    const int lane = threadIdx.x & 31;
    int r = blockIdx.x * 8 + (threadIdx.x >> 5);
    if (r >= n) return;

    int e0 = off[r], e1 = off[r + 1];
    float4 acc = make_float4(0.f, 0.f, 0.f, 0.f);
    for (int e = e0; e < e1; ++e) {
        int2 cv = edge_s[e];
        float v = __int_as_float(cv.y);
        float4 x = *(const float4*)(X + (size_t)cv.x * EMB + lane * 4);
        acc.x += v * x.x;
        acc.y += v * x.y;
        acc.z += v * x.z;
        acc.w += v * x.w;
    }
    *(float4*)(out + (size_t)r * EMB + lane * 4) = acc;  // writes zero rows too
}

// ---------------- In-place projection: out[r,:] = out[r,:] @ W ----------------

__global__ __launch_bounds__(256) void gemm_inplace(float* __restrict__ out,
                                                    const float* __restrict__ W,
                                                    int n) {
    __shared__ float Wl[EMB * EMB];   // 64 KB
    __shared__ float Al[8 * EMB];     // 4 KB
    const int tid = threadIdx.x;

    for (int i = tid; i < EMB * EMB / 4; i += 256)
        ((float4*)Wl)[i] = ((const float4*)W)[i];

    const int j4   = (tid & 31) * 4;
    const int rsub = tid >> 5;

    for (int rb = blockIdx.x * 8; rb < n; rb += gridDim.x * 8) {
        __syncthreads();
        {
            int nrows = min(8, n - rb);
            int nfl = nrows * EMB / 4;
            if (tid < nfl)
                ((float4*)Al)[tid] = ((const float4*)(out + (size_t)rb * EMB))[tid];
        }
        __syncthreads();

        int r = rb + rsub;
        if (r < n) {
            float4 acc = make_float4(0.f, 0.f, 0.f, 0.f);
            const float* ar = Al + rsub * EMB;
#pragma unroll 4
            for (int k = 0; k < EMB; ++k) {
                float a = ar[k];
                float4 w = *(const float4*)(Wl + k * EMB + j4);
                acc.x += a * w.x;
                acc.y += a * w.y;
                acc.z += a * w.z;
                acc.w += a * w.w;
            }
            *(float4*)(out + (size_t)r * EMB + j4) = acc;
        }
    }
}

// ---------------- Fallback (Round-2 passing path) ----------------

__global__ __launch_bounds__(256) void scatter_edges(const float* __restrict__ X,
                                                     const float* __restrict__ ev,
                                                     const int* __restrict__ er,
                                                     const int* __restrict__ ec,
                                                     float* __restrict__ out,
                                                     int nedges) {
    const int lane = threadIdx.x & 31;
    long long e = (long long)blockIdx.x * 8 + (threadIdx.x >> 5);
    if (e >= nedges) return;
    const int r = er[e];
    const int c = ec[e];
    const float v = ev[e];
    float4 x = *(const float4*)(X + (size_t)c * EMB + lane * 4);
    float* o = out + (size_t)r * EMB + lane * 4;
    unsafeAtomicAdd(o + 0, v * x.x);
    unsafeAtomicAdd(o + 1, v * x.y);
    unsafeAtomicAdd(o + 2, v * x.z);
    unsafeAtomicAdd(o + 3, v * x.w);
}

extern "C" void kernel_launch(void* const* d_in, const int* in_sizes, int n_in,
                              void* d_out, int out_size, void* d_ws, size_t ws_size,
                              hipStream_t stream) {
    const float* X  = (const float*)d_in[0];
    const float* W  = (const float*)d_in[1];
    const float* ev = (const float*)d_in[2];
    const int*   er = (const int*)d_in[3];
    const int*   ec = (const int*)d_in[4];

    const int n  = in_sizes[0] / EMB;   // 100000
    const int ne = in_sizes[2];         // 3200000

    float* out = (float*)d_out;

    // Workspace layout: counts[n+1] | off[n+1] | cursor[n+1] | pad | edge_s[ne] (int2)
    size_t need = (size_t)3 * (n + 1) * sizeof(int) + 16 + (size_t)ne * sizeof(int2);

    if (ws_size >= need) {
        int* counts = (int*)d_ws;
        int* off    = counts + (n + 1);
        int* cursor = off + (n + 1);
        uintptr_t p = (uintptr_t)(cursor + (n + 1));
        p = (p + 7) & ~(uintptr_t)7;
        int2* edge_s = (int2*)p;

        hipMemsetAsync(counts, 0, (size_t)(n + 1) * sizeof(int), stream);
        hist_rows<<<2048, 256, 0, stream>>>(er, counts, ne);
        scan_offsets<<<1, 1024, 0, stream>>>(counts, off, cursor, n);
        sort_edges<<<2048, 256, 0, stream>>>(er, ec, ev, cursor, edge_s, ne);
        pull_rows<<<(n + 7) / 8, 256, 0, stream>>>(X, off, edge_s, out, n);
        gemm_inplace<<<2048, 256, 0, stream>>>(out, W, n);
    } else {
        // Fallback: atomic scatter (passed Round 2)
        hipMemsetAsync(out, 0, (size_t)n * EMB * sizeof(float), stream);
        int nblk = (ne + 7) / 8;
        scatter_edges<<<nblk, 256, 0, stream>>>(X, ev, er, ec, out, ne);
        gemm_inplace<<<2048, 256, 0, stream>>>(out, W, n);
    }
}